// Round 1
// baseline (561.902 us; speedup 1.0000x reference)
//
#include <hip/hip_runtime.h>
#include <hip/hip_bf16.h>
#include <cstdint>

// Problem constants (fixed by the reference).
#define B_   16
#define C_   306
#define T_   4096
#define M_   270
#define G_   64     // 8x8 grid, strides {8,1}

#define BDIM 256    // 4 waves per block
#define NW   4      // waves per block
#define TT   64     // t-tile per block (= one wave width)

// ---------------------------------------------------------------------------
// Setup kernel: per (b,c) compute packed 4 corner indices + 4 bilinear weights.
// Corner order matches itertools.product((0,1),repeat=2):
//   (lo,lo), (lo,hi), (hi,lo), (hi,hi)  with dim0 stride 8, dim1 stride 1.
// ---------------------------------------------------------------------------
__global__ void setup_corners(const float* __restrict__ pos,
                              uint32_t* __restrict__ cidx,
                              float4* __restrict__ cw) {
    int i = blockIdx.x * blockDim.x + threadIdx.x;
    if (i >= B_ * C_) return;
    float p0 = pos[i * 2 + 0];
    float p1 = pos[i * 2 + 1];
    float gp0 = (p0 + 1.0f) * 4.0f;   // (p+1)*grid_size/2, grid_size=8
    float gp1 = (p1 + 1.0f) * 4.0f;
    float f0 = floorf(gp0), f1 = floorf(gp1);
    int l0 = (int)f0, l1 = (int)f1;
    int h0 = (int)ceilf(gp0), h1 = (int)ceilf(gp1);
    float wh0 = gp0 - f0, wh1 = gp1 - f1;
    float wl0 = 1.0f - wh0, wl1 = 1.0f - wh1;
    uint32_t i00 = (uint32_t)(l0 * 8 + l1);
    uint32_t i01 = (uint32_t)(l0 * 8 + h1);
    uint32_t i10 = (uint32_t)(h0 * 8 + l1);
    uint32_t i11 = (uint32_t)(h0 * 8 + h1);
    cidx[i] = i00 | (i01 << 8) | (i10 << 16) | (i11 << 24);
    cw[i] = make_float4(wl0 * wl1, wl0 * wh1, wh0 * wl1, wh0 * wh1);
}

// ---------------------------------------------------------------------------
// Fused kernel: one block per (b, 64-wide t tile).
//   Phase 1: scatter x[b,c,t]*w into LDS gv[64][64]  (index uniform per block)
//   Phase 2: out[b,m,t] = sum_g W[m,g] * gv[g][t]    (W via scalar loads)
// ---------------------------------------------------------------------------
__global__ __launch_bounds__(BDIM) void fused_grid_gemm(
    const float* __restrict__ x, const float* __restrict__ gw,
    const uint32_t* __restrict__ cidx, const float4* __restrict__ cw,
    float* __restrict__ out) {
    __shared__ float gv[G_ * TT];   // [g][t] layout: lanes stride-1 -> no bank conflicts

    const int b    = blockIdx.y;
    const int t0   = blockIdx.x * TT;
    const int lane = threadIdx.x & 63;
    // readfirstlane: force wave-uniformity so c / m become scalar -> s_load for
    // corner data and W rows instead of per-lane broadcast vector loads.
    const int wave = __builtin_amdgcn_readfirstlane(threadIdx.x >> 6);
    const int t    = t0 + lane;
    const int bC   = b * C_;

    // zero gv
    for (int i = threadIdx.x; i < G_ * TT; i += BDIM) gv[i] = 0.0f;
    __syncthreads();

    // ---- Phase 1: scatter (waves split the c loop) ----
    const float* xrow = x + (size_t)bC * T_ + t;
    {
        int c = wave;
        #pragma unroll 4
        for (; c < C_; c += NW) {
            uint32_t pk = cidx[bC + c];     // uniform -> s_load
            float4   w  = cw[bC + c];       // uniform -> s_load_dwordx4
            float val = xrow[(size_t)c * T_];   // coalesced across lanes
            atomicAdd(&gv[((pk      ) & 63) * TT + lane], w.x * val);
            atomicAdd(&gv[((pk >>  8) & 63) * TT + lane], w.y * val);
            atomicAdd(&gv[((pk >> 16) & 63) * TT + lane], w.z * val);
            atomicAdd(&gv[((pk >> 24) & 63) * TT + lane], w.w * val);
        }
    }
    __syncthreads();

    // ---- Phase 2: per-thread gv column in registers, waves split m ----
    float gvr[G_];
    #pragma unroll
    for (int g = 0; g < G_; ++g) gvr[g] = gv[g * TT + lane];

    const int m0 = wave * 68;
    const int m1 = (wave == NW - 1) ? M_ : (m0 + 68);
    float* op = out + (size_t)b * M_ * T_ + t;
    for (int m = m0; m < m1; ++m) {
        const float* wr = gw + (m << 6);    // uniform row -> s_load_dwordx16
        float a0 = 0.f, a1 = 0.f, a2 = 0.f, a3 = 0.f;
        #pragma unroll
        for (int g = 0; g < G_; g += 4) {
            a0 += wr[g + 0] * gvr[g + 0];
            a1 += wr[g + 1] * gvr[g + 1];
            a2 += wr[g + 2] * gvr[g + 2];
            a3 += wr[g + 3] * gvr[g + 3];
        }
        op[(size_t)m * T_] = (a0 + a1) + (a2 + a3);
    }
}

extern "C" void kernel_launch(void* const* d_in, const int* in_sizes, int n_in,
                              void* d_out, int out_size, void* d_ws, size_t ws_size,
                              hipStream_t stream) {
    const float* x   = (const float*)d_in[0];
    const float* pos = (const float*)d_in[1];
    const float* gw  = (const float*)d_in[2];
    float* out = (float*)d_out;

    // workspace layout: [ cw: B*C float4 | cidx: B*C uint32 ]  (~98 KB)
    float4*   cw   = (float4*)d_ws;
    uint32_t* cidx = (uint32_t*)((char*)d_ws + (size_t)B_ * C_ * sizeof(float4));

    setup_corners<<<(B_ * C_ + 255) / 256, 256, 0, stream>>>(pos, cidx, cw);

    dim3 grid(T_ / TT, B_);
    fused_grid_gemm<<<grid, BDIM, 0, stream>>>(x, gw, cidx, cw, out);
}